// Round 4
// baseline (433.938 us; speedup 1.0000x reference)
//
#include <hip/hip_runtime.h>

// SparseMeshConv fused kernel, R6 (MI355X / gfx950)
//   patch = [x, |a-c|, a+c, |b-d|, b+d]  (a=x[idx1], b=x[idx2], c=x[idx3], d=x[idx4])
//   y = LN(patch @ W + bias) * gamma + beta + x;  out = gelu_erf(y)
// R6 vs R5 (203 us, MfmaUtil 13.3 / VALU 24 / HBM 25% -> ~90% SIMD idle):
//  - ROW-split waves: each wave owns 16 rows x 256 cols. A-fragment for
//    mfma_16x16x32 is lane-local (row=l16, k=quad*8+e) -> each lane direct-loads
//    its own 32B row slice. NO LDS, NO ds ops, NO s_barrier in the entire kernel.
//    (R2-R5 column-split forced LDS A-broadcast + 40 lockstep barriers coupling
//    4 SIMDs with independent congestion -> ~2000cyc/iter walls.)
//  - Per-wave pipeline: self slices ring-2 (2-chunk cover), pair gathers single
//    slot issued 2 chunks ahead, W streamed as 2x8 fragments/chunk from
//    L2-resident Wt (16 KB/chunk/wave).
//  - LN epilogue wave-local: in-register ni-reduction + shfl_xor(1,2,4,8) within
//    16-lane groups; cross-wave LDS reduction gone.
//  - Cost accepted: W L2 traffic x4 (4 GB total, ~30 TB/s at target) - next wall.

#define N_ROWS   100000
#define C        256
#define BK       32
#define NCHUNK   40      // 1280 / 32
#define BM       64
#define LN_EPS   1e-5f

typedef __bf16 bf16;
typedef bf16  bf16x8 __attribute__((ext_vector_type(8)));
typedef float f32x4  __attribute__((ext_vector_type(4)));

union BV  { bf16x8 v; bf16 h[8]; };
union FV2 { float4 q[2]; float f[8]; };

// K-chunk -> original W row mapping (BK=32):
//  kc 0..7   : x slice            kRow = kc*32 + kk
//  kc 8..23  : u=kc-8             kRow = 256 + (u&1)*256 + (u>>1)*32 + kk   (|a-c| / a+c)
//  kc 24..39 : u=kc-24            kRow = 768 + (u&1)*256 + (u>>1)*32 + kk   (|b-d| / b+d)
// Wt layout = exact MFMA B-fragment order, one bf16x8 per (kc,f,lane), f=0..15:
//  Wt[(kc*16 + f)*64 + lane] .h[e] = W[kRow(kc, (lane>>4)*8+e)][col(f,lane)]
//  col(f,lane) = (f>>2)*64 + (f&3)*16 + (lane&15)
__global__ void wprep(const float* __restrict__ W, bf16* __restrict__ Wt) {
    int t = blockIdx.x * 256 + threadIdx.x;
    if (t >= NCHUNK * 16 * 64) return;             // 40960 granules
    int lane = t & 63;
    int f    = (t >> 6) & 15;
    int kc   = t >> 10;
    int l16  = lane & 15, quad = lane >> 4;
    int n = ((f >> 2) << 6) + ((f & 3) << 4) + l16;
    int base;
    if (kc < 8)       base = kc * 32;
    else if (kc < 24) { int u = kc - 8;  base = 256 + (u & 1) * 256 + (u >> 1) * 32; }
    else              { int u = kc - 24; base = 768 + (u & 1) * 256 + (u >> 1) * 32; }
    BV o;
    #pragma unroll
    for (int e = 0; e < 8; ++e) {
        int kRow = base + quad * 8 + e;
        o.h[e] = (bf16)W[(size_t)kRow * C + n];
    }
    ((bf16x8*)Wt)[t] = o.v;
}

// issue both rows of pair P into (pal, pcl); P<8 -> (idx1,idx3) else (idx2,idx4)
#define ISSUE_PAIR(P) do {                                                            \
    const float* _ba = x + (size_t)((P) < 8 ? ia : ib) * C + (((P) & 7) << 5) + (quad << 3); \
    const float* _bc = x + (size_t)((P) < 8 ? ic : id) * C + (((P) & 7) << 5) + (quad << 3); \
    pal.q[0] = ((const float4*)_ba)[0]; pal.q[1] = ((const float4*)_ba)[1];           \
    pcl.q[0] = ((const float4*)_bc)[0]; pcl.q[1] = ((const float4*)_bc)[1];           \
} while (0)

__global__ __launch_bounds__(256, 3)
void fused(const float* __restrict__ x,
           const int* __restrict__ idx1, const int* __restrict__ idx2,
           const int* __restrict__ idx3, const int* __restrict__ idx4,
           const bf16* __restrict__ Wt,
           const float* __restrict__ bias,
           const float* __restrict__ gamma_, const float* __restrict__ beta_,
           float* __restrict__ out)
{
    const int tid  = threadIdx.x;
    const int lane = tid & 63;
    const int wv   = tid >> 6;       // wave -> 16-row group
    const int quad = lane >> 4;      // k-window within chunk (quad*8)
    const int l16  = lane & 15;      // A row within the wave's 16-row tile
    const int r0   = blockIdx.x * BM;

    // this lane's load row (A side): r0 + wv*16 + l16
    int r_ld = r0 + wv * 16 + l16; if (r_ld >= N_ROWS) r_ld = 0;
    const int ia = idx1[r_ld], ib = idx2[r_ld];
    const int ic = idx3[r_ld], id = idx4[r_ld];
    const float* xrow = x + (size_t)r_ld * C + (quad << 3);

    // per-lane W fragment pointer: frag f of chunk kc at Wq[(kc*16+f)*64]
    const bf16x8* Wq = (const bf16x8*)Wt + lane;

    f32x4 acc[16] = {};              // acc[f]: cols (f>>2)*64+(f&3)*16+l16
    bf16x8 wf[8];
    bf16x8 af, af_hold;
    FV2 s0l, s1l;                    // self landing ring (slices kc: even->s0l, odd->s1l)
    FV2 pal, pcl;                    // pair landing (single slot, 2-chunk cover)

    // ---- prologue: issue self slices 0 and 1
    {
        const float4* p0 = (const float4*)xrow;
        s0l.q[0] = p0[0]; s0l.q[1] = p0[1];
        const float4* p1 = (const float4*)(xrow + 32);
        s1l.q[0] = p1[0]; s1l.q[1] = p1[1];
    }

    #pragma unroll
    for (int kc = 0; kc < NCHUNK; ++kc) {
        // ---- W half-0 fragment loads (L2-resident)
        #pragma unroll
        for (int f = 0; f < 8; ++f) wf[f] = Wq[(kc * 16 + f) * 64];

        // ---- produce af for chunk kc; issue next A loads
        if (kc < 8) {
            BV t;
            if (kc & 1) {
                #pragma unroll
                for (int j = 0; j < 8; ++j) t.h[j] = (bf16)s1l.f[j];
            } else {
                #pragma unroll
                for (int j = 0; j < 8; ++j) t.h[j] = (bf16)s0l.f[j];
            }
            af = t.v;
            if (kc < 6) {            // issue self slice kc+2 into same ring slot
                const float4* p = (const float4*)(xrow + ((kc + 2) << 5));
                if (kc & 1) { s1l.q[0] = p[0]; s1l.q[1] = p[1]; }
                else        { s0l.q[0] = p[0]; s0l.q[1] = p[1]; }
            } else if (kc == 6) {
                ISSUE_PAIR(0);       // pair 0 needed at kc=8
            }
        } else if (!((kc - 8) & 1)) {
            const int p = (kc < 24) ? ((kc - 8) >> 1) : (((kc - 24) >> 1) + 8);
            BV d, s;
            #pragma unroll
            for (int j = 0; j < 8; ++j) {
                d.h[j] = (bf16)fabsf(pal.f[j] - pcl.f[j]);
                s.h[j] = (bf16)(pal.f[j] + pcl.f[j]);
            }
            af = d.v; af_hold = s.v;
            if (p < 15) ISSUE_PAIR(p + 1);   // consume-then-issue, 2-chunk cover
        } else {
            af = af_hold;
        }

        // ---- MFMA half-0 (frags 0..7)
        __builtin_amdgcn_s_setprio(1);
        #pragma unroll
        for (int f = 0; f < 8; ++f)
            acc[f] = __builtin_amdgcn_mfma_f32_16x16x32_bf16(af, wf[f], acc[f], 0, 0, 0);
        __builtin_amdgcn_s_setprio(0);

        // ---- W half-1 fragment loads (reuse wf; in-order issue after MFMA reads)
        #pragma unroll
        for (int f = 0; f < 8; ++f) wf[f] = Wq[(kc * 16 + 8 + f) * 64];

        // ---- MFMA half-1 (frags 8..15)
        __builtin_amdgcn_s_setprio(1);
        #pragma unroll
        for (int f = 0; f < 8; ++f)
            acc[8 + f] = __builtin_amdgcn_mfma_f32_16x16x32_bf16(af, wf[f], acc[8 + f], 0, 0, 0);
        __builtin_amdgcn_s_setprio(0);
    }

    // ---- epilogue (wave-local, no LDS): +bias, LN stats, normalize, residual, GELU
    // acc[f][rg] is C[row = quad*4+rg (+wv*16+r0)][col = (f>>2)*64+(f&3)*16+l16]
    float bc[16];
    #pragma unroll
    for (int f = 0; f < 16; ++f) {
        int cidx = ((f >> 2) << 6) + ((f & 3) << 4) + l16;
        bc[f] = bias[cidx];
    }
    #pragma unroll
    for (int f = 0; f < 16; ++f)
        #pragma unroll
        for (int rg = 0; rg < 4; ++rg)
            acc[f][rg] += bc[f];

    float mu[4], rs[4];
    #pragma unroll
    for (int rg = 0; rg < 4; ++rg) {
        float s = 0.f, q = 0.f;
        #pragma unroll
        for (int f = 0; f < 16; ++f) {
            float y = acc[f][rg];
            s += y; q += y * y;
        }
        // reduce across the 16 lanes of this quad (cols l16 of each 16-block)
        #pragma unroll
        for (int m = 1; m <= 8; m <<= 1) {
            s += __shfl_xor(s, m, 64);
            q += __shfl_xor(q, m, 64);
        }
        float m_  = s * (1.0f / C);
        float var = q * (1.0f / C) - m_ * m_;
        mu[rg] = m_;
        rs[rg] = rsqrtf(var + LN_EPS);
    }

    float gc[16], ec[16];
    #pragma unroll
    for (int f = 0; f < 16; ++f) {
        int cidx = ((f >> 2) << 6) + ((f & 3) << 4) + l16;
        gc[f] = gamma_[cidx]; ec[f] = beta_[cidx];
    }

    #pragma unroll
    for (int rg = 0; rg < 4; ++rg) {
        int grow = r0 + wv * 16 + quad * 4 + rg;
        if (grow >= N_ROWS) continue;
        const float* xr = x   + (size_t)grow * C;
        float*       orw = out + (size_t)grow * C;
        #pragma unroll
        for (int f = 0; f < 16; ++f) {
            int cidx = ((f >> 2) << 6) + ((f & 3) << 4) + l16;
            float y = (acc[f][rg] - mu[rg]) * rs[rg] * gc[f] + ec[f];
            y += xr[cidx];
            float g = 0.5f * y * (1.0f + erff(y * 0.70710678118654752f));
            orw[cidx] = g;
        }
    }
}

extern "C" void kernel_launch(void* const* d_in, const int* in_sizes, int n_in,
                              void* d_out, int out_size, void* d_ws, size_t ws_size,
                              hipStream_t stream) {
    const float* x  = (const float*)d_in[0];
    const int*   i1 = (const int*)d_in[1];
    const int*   i2 = (const int*)d_in[2];
    const int*   i3 = (const int*)d_in[3];
    const int*   i4 = (const int*)d_in[4];
    const float* W  = (const float*)d_in[5];
    const float* b  = (const float*)d_in[6];
    const float* gm = (const float*)d_in[7];
    const float* bt = (const float*)d_in[8];
    float* outp = (float*)d_out;
    bf16* Wt = (bf16*)d_ws;   // 40*16*64*16 B = 640 KB, fragment-order bf16 W

    wprep<<<(NCHUNK * 16 * 64 + 255) / 256, 256, 0, stream>>>(W, Wt);
    fused<<<(N_ROWS + BM - 1) / BM, 256, 0, stream>>>(
        x, i1, i2, i3, i4, Wt, b, gm, bt, outp);
}

// Round 5
// 339.873 us; speedup vs baseline: 1.2768x; 1.2768x over previous
//
#include <hip/hip_runtime.h>

// SparseMeshConv fused kernel, R7 (MI355X / gfx950)
//   patch = [x, |a-c|, a+c, |b-d|, b+d]  (a=x[idx1], b=x[idx2], c=x[idx3], d=x[idx4])
//   y = LN(patch @ W + bias) * gamma + beta + x;  out = gelu_erf(y)
// R7 vs R5 (203 us) / R6 (335 us, row-split FAILED: 4x W traffic + exposed W latency):
//  - Back to column-split + LDS A-tiles (R5 dataflow), but TWO 32-k chunks per
//    barrier interval: 20 iterations, 32 MFMA + 1 barrier each (R5: 16 MFMA/bar,
//    40 bars). Per-iteration structural overhead (barrier skew, VMEM->VALU->LDS
//    round-trips) halves.
//  - K-layout gift: chunks (8+2p, 9+2p) = (|a-c| slice p, a+c slice p) -> one
//    iteration loads one neighbor-pair slice and stages BOTH chunks; 'hold'
//    register gone; gathers issued 2 iterations (=4 chunks) ahead.
//  - W: 8 frags/iter loaded at iteration top (>=300cyc before first MFMA use),
//    L2-resident. Regs ~= R5 (wf8 replaces wf4+wfn4). LDS 16 KB (2x2 tiles).

#define N_ROWS   100000
#define C        256
#define BK       32
#define NCHUNK   40      // 1280 / 32
#define NITER    20      // 2 chunks per iteration
#define BM       64
#define CHUNK_V  1024    // bf16x8 granules per K-chunk in Wt (4 wv * 4 ni * 64 lanes)
#define LN_EPS   1e-5f

typedef __bf16 bf16;
typedef bf16  bf16x8 __attribute__((ext_vector_type(8)));
typedef float f32x4  __attribute__((ext_vector_type(4)));

union BV  { bf16x8 v; bf16 h[8]; };
union FV2 { float4 q[2]; float f[8]; };

// LDS-visibility barrier that keeps vmcnt COUNTED (no "memory" clobber).
__device__ __forceinline__ void lds_barrier() {
    __builtin_amdgcn_sched_barrier(0);
    asm volatile("s_waitcnt lgkmcnt(0)");
    __builtin_amdgcn_s_barrier();
    __builtin_amdgcn_sched_barrier(0);
}

// K-chunk -> original W row mapping (BK=32):
//  kc 0..7   : x slice            kRow = kc*32 + kk
//  kc 8..23  : u=kc-8             kRow = 256 + (u&1)*256 + (u>>1)*32 + kk   (|a-c| / a+c)
//  kc 24..39 : u=kc-24            kRow = 768 + (u&1)*256 + (u>>1)*32 + kk   (|b-d| / b+d)
// Wt layout = exact MFMA B-fragment order, one bf16x8 per (kc,wv,ni,lane):
//  Wt[((kc*4 + wv)*4 + ni)*64 + lane] .h[e] = W[kRow(kc, (lane>>4)*8+e)][wv*64+ni*16+(lane&15)]
__global__ void wprep(const float* __restrict__ W, bf16* __restrict__ Wt) {
    int t = blockIdx.x * 256 + threadIdx.x;
    if (t >= NCHUNK * 4 * 4 * 64) return;          // 40960 granules
    int lane = t & 63;
    int ni   = (t >> 6) & 3;
    int wv   = (t >> 8) & 3;
    int kc   = t >> 10;
    int l16  = lane & 15, quad = lane >> 4;
    int n = wv * 64 + ni * 16 + l16;
    int base;
    if (kc < 8)       base = kc * 32;
    else if (kc < 24) { int u = kc - 8;  base = 256 + (u & 1) * 256 + (u >> 1) * 32; }
    else              { int u = kc - 24; base = 768 + (u & 1) * 256 + (u >> 1) * 32; }
    BV o;
    #pragma unroll
    for (int e = 0; e < 8; ++e) {
        int kRow = base + quad * 8 + e;
        o.h[e] = (bf16)W[(size_t)kRow * C + n];
    }
    ((bf16x8*)Wt)[t] = o.v;
}

__global__ __launch_bounds__(256, 3)
void fused(const float* __restrict__ x,
           const int* __restrict__ idx1, const int* __restrict__ idx2,
           const int* __restrict__ idx3, const int* __restrict__ idx4,
           const bf16* __restrict__ Wt,
           const float* __restrict__ bias,
           const float* __restrict__ gamma_, const float* __restrict__ beta_,
           float* __restrict__ out)
{
    __shared__ __align__(16) union {
        bf16 a[2][2][BM * BK];                          // [iterbuf][sub][64*32] = 16 KB
        struct { float rsum[BM][4]; float rsq[BM][4]; float mu[BM]; float rs[BM]; } red;
    } SA;
    // red (2560 B) overlays a[0]; the last MFMA (i=19) reads a[1] (disjoint) ->
    // no epilogue/A-tile hazard even with wave skew.

    const int tid  = threadIdx.x;
    const int lane = tid & 63;
    const int wv   = tid >> 6;       // wave -> column group (wv*64)
    const int quad = lane >> 4;
    const int l16  = lane & 15;
    const int r0   = blockIdx.x * BM;

    const int r_st = tid >> 2;       // staging row 0..63
    const int q_st = tid & 3;        // 8-float eighth of the 32-col slice
    int gr_self = r0 + r_st; if (gr_self >= N_ROWS) gr_self = 0;
    const int ia = idx1[gr_self], ib = idx2[gr_self];
    const int ic = idx3[gr_self], id = idx4[gr_self];
    const float* xself = x + (size_t)gr_self * C + (q_st << 3);

    const int a_w_off = r_st * 32 + ((q_st ^ ((r_st >> 1) & 3)) << 3);
    int a_r_off[4];
    #pragma unroll
    for (int mi = 0; mi < 4; ++mi) {
        int m = mi * 16 + l16;
        a_r_off[mi] = m * 32 + ((quad ^ ((m >> 1) & 3)) << 3);
    }

    // per-lane W fragment pointer: Wq[kc*1024 + ni*64] is this lane's bf16x8
    const bf16x8* Wq = (const bf16x8*)Wt + wv * 256 + lane;

    f32x4 acc[4][4] = {};
    bf16x8 wf[8];
    FV2 cA, cB;                      // data for iteration i+1 (staged this iteration)
    FV2 nA, nB;                      // data for iteration i+2 (issued this iteration)

    // ---- prologue: stage iteration 0 (self slices 0,1); issue iteration-1 loads
    {
        const float4* p0 = (const float4*)xself;
        const float4* p1 = (const float4*)(xself + 32);
        FV2 u0, u1;
        u0.q[0] = p0[0]; u0.q[1] = p0[1];
        u1.q[0] = p1[0]; u1.q[1] = p1[1];
        const float4* p2 = (const float4*)(xself + 64);   // iter-1: slices 2,3
        const float4* p3 = (const float4*)(xself + 96);
        cA.q[0] = p2[0]; cA.q[1] = p2[1];
        cB.q[0] = p3[0]; cB.q[1] = p3[1];
        BV b0, b1;
        #pragma unroll
        for (int j = 0; j < 8; ++j) { b0.h[j] = (bf16)u0.f[j]; b1.h[j] = (bf16)u1.f[j]; }
        *(bf16x8*)&SA.a[0][0][a_w_off] = b0.v;
        *(bf16x8*)&SA.a[0][1][a_w_off] = b1.v;
    }
    lds_barrier();

    #pragma unroll
    for (int i = 0; i < NITER; ++i) {
        // ---- 1. W fragments for chunks 2i, 2i+1 (L2-resident; used after stage+bar)
        {
            const bf16x8* w0 = Wq + (size_t)(2 * i)     * CHUNK_V;
            const bf16x8* w1 = Wq + (size_t)(2 * i + 1) * CHUNK_V;
            #pragma unroll
            for (int j = 0; j < 4; ++j) { wf[j] = w0[j * 64]; wf[4 + j] = w1[j * 64]; }
        }

        // ---- 2. issue A loads for iteration i+2 (4-chunk latency cover)
        const int jp = i + 2;
        if (jp < NITER) {
            if (jp < 4) {
                const float4* pa = (const float4*)(xself + ((2 * jp)     << 5));
                const float4* pb = (const float4*)(xself + ((2 * jp + 1) << 5));
                nA.q[0] = pa[0]; nA.q[1] = pa[1];
                nB.q[0] = pb[0]; nB.q[1] = pb[1];
            } else {
                const int p   = (jp < 12) ? (jp - 4) : (jp - 12);
                const int rA  = (jp < 12) ? ia : ib;
                const int rC  = (jp < 12) ? ic : id;
                const int off = (p << 5) + (q_st << 3);
                const float4* pa = (const float4*)(x + (size_t)rA * C + off);
                const float4* pc = (const float4*)(x + (size_t)rC * C + off);
                nA.q[0] = pa[0]; nA.q[1] = pa[1];
                nB.q[0] = pc[0]; nB.q[1] = pc[1];
            }
        }

        // ---- 3. stage iteration i+1 (both sub-chunks) from regs loaded LAST iter
        const int jn = i + 1;
        if (jn < NITER) {
            BV s0, s1;
            if (jn < 4) {            // self: slices 2jn, 2jn+1
                #pragma unroll
                for (int j = 0; j < 8; ++j) {
                    s0.h[j] = (bf16)cA.f[j];
                    s1.h[j] = (bf16)cB.f[j];
                }
            } else {                 // pair: |A-C| then A+C
                #pragma unroll
                for (int j = 0; j < 8; ++j) {
                    s0.h[j] = (bf16)fabsf(cA.f[j] - cB.f[j]);
                    s1.h[j] = (bf16)(cA.f[j] + cB.f[j]);
                }
            }
            *(bf16x8*)&SA.a[jn & 1][0][a_w_off] = s0.v;
            *(bf16x8*)&SA.a[jn & 1][1][a_w_off] = s1.v;
        }

        // ---- 4. MFMA: sub-chunk 0 then sub-chunk 1 (32 MFMAs per barrier)
        {
            const bf16* Ab0 = SA.a[i & 1][0];
            const bf16* Ab1 = SA.a[i & 1][1];
            bf16x8 af[4];
            #pragma unroll
            for (int mi = 0; mi < 4; ++mi)
                af[mi] = *(const bf16x8*)&Ab0[a_r_off[mi]];
            __builtin_amdgcn_s_setprio(1);
            #pragma unroll
            for (int mi = 0; mi < 4; ++mi)
                #pragma unroll
                for (int ni = 0; ni < 4; ++ni)
                    acc[mi][ni] = __builtin_amdgcn_mfma_f32_16x16x32_bf16(
                        af[mi], wf[ni], acc[mi][ni], 0, 0, 0);
            __builtin_amdgcn_s_setprio(0);
            #pragma unroll
            for (int mi = 0; mi < 4; ++mi)
                af[mi] = *(const bf16x8*)&Ab1[a_r_off[mi]];
            __builtin_amdgcn_s_setprio(1);
            #pragma unroll
            for (int mi = 0; mi < 4; ++mi)
                #pragma unroll
                for (int ni = 0; ni < 4; ++ni)
                    acc[mi][ni] = __builtin_amdgcn_mfma_f32_16x16x32_bf16(
                        af[mi], wf[4 + ni], acc[mi][ni], 0, 0, 0);
            __builtin_amdgcn_s_setprio(0);
        }

        // ---- 5. rotate; barrier (lgkmcnt-only; vmcnt stays counted)
        cA = nA; cB = nB;
        if (i < NITER - 1) lds_barrier();
    }

    // ---- epilogue: +bias, LN stats, normalize, residual, exact GELU
    float bcol[4], gcol[4], ecol[4];
    #pragma unroll
    for (int ni = 0; ni < 4; ++ni) {
        int cidx = wv * 64 + ni * 16 + l16;
        bcol[ni] = bias[cidx]; gcol[ni] = gamma_[cidx]; ecol[ni] = beta_[cidx];
    }
    #pragma unroll
    for (int mi = 0; mi < 4; ++mi)
        #pragma unroll
        for (int ni = 0; ni < 4; ++ni)
            #pragma unroll
            for (int rg = 0; rg < 4; ++rg)
                acc[mi][ni][rg] += bcol[ni];

    #pragma unroll
    for (int mi = 0; mi < 4; ++mi) {
        #pragma unroll
        for (int rg = 0; rg < 4; ++rg) {
            float s = 0.f, q = 0.f;
            #pragma unroll
            for (int ni = 0; ni < 4; ++ni) {
                float y = acc[mi][ni][rg];
                s += y; q += y * y;
            }
            #pragma unroll
            for (int m = 1; m <= 8; m <<= 1) {
                s += __shfl_xor(s, m, 64);
                q += __shfl_xor(q, m, 64);
            }
            if (l16 == 0) {
                int row = mi * 16 + quad * 4 + rg;
                SA.red.rsum[row][wv] = s;
                SA.red.rsq [row][wv] = q;
            }
        }
    }
    __syncthreads();
    if (tid < BM) {
        float s  = SA.red.rsum[tid][0] + SA.red.rsum[tid][1] + SA.red.rsum[tid][2] + SA.red.rsum[tid][3];
        float q  = SA.red.rsq [tid][0] + SA.red.rsq [tid][1] + SA.red.rsq [tid][2] + SA.red.rsq [tid][3];
        float mu = s * (1.0f / C);
        float var = q * (1.0f / C) - mu * mu;
        SA.red.mu[tid] = mu;
        SA.red.rs[tid] = rsqrtf(var + LN_EPS);
    }
    __syncthreads();

    #pragma unroll
    for (int mi = 0; mi < 4; ++mi) {
        #pragma unroll
        for (int rg = 0; rg < 4; ++rg) {
            int row  = mi * 16 + quad * 4 + rg;
            int grow = r0 + row;
            if (grow >= N_ROWS) continue;
            float mu = SA.red.mu[row], rs = SA.red.rs[row];
            #pragma unroll
            for (int ni = 0; ni < 4; ++ni) {
                int cidx = wv * 64 + ni * 16 + l16;
                float y = (acc[mi][ni][rg] - mu) * rs * gcol[ni] + ecol[ni];
                y += x[(size_t)grow * C + cidx];
                float g = 0.5f * y * (1.0f + erff(y * 0.70710678118654752f));
                out[(size_t)grow * C + cidx] = g;
            }
        }
    }
}

extern "C" void kernel_launch(void* const* d_in, const int* in_sizes, int n_in,
                              void* d_out, int out_size, void* d_ws, size_t ws_size,
                              hipStream_t stream) {
    const float* x  = (const float*)d_in[0];
    const int*   i1 = (const int*)d_in[1];
    const int*   i2 = (const int*)d_in[2];
    const int*   i3 = (const int*)d_in[3];
    const int*   i4 = (const int*)d_in[4];
    const float* W  = (const float*)d_in[5];
    const float* b  = (const float*)d_in[6];
    const float* gm = (const float*)d_in[7];
    const float* bt = (const float*)d_in[8];
    float* outp = (float*)d_out;
    bf16* Wt = (bf16*)d_ws;   // 40*1024*16 = 640 KB, fragment-order bf16 W

    wprep<<<(NCHUNK * 4 * 4 * 64 + 255) / 256, 256, 0, stream>>>(W, Wt);
    fused<<<(N_ROWS + BM - 1) / BM, 256, 0, stream>>>(
        x, i1, i2, i3, i4, Wt, b, gm, bt, outp);
}